// Round 1
// 166.920 us; speedup vs baseline: 1.0014x; 1.0014x over previous
//
#include <hip/hip_runtime.h>

#define NQ      10
#define NLAYERS 4
#define D_IN    784
#define BLOCK   256            // R13: 4 waves per workgroup, ONE state per wave.
// R13 theory: the old 2-state/wave layout needed ~128 regs (64 VGPR + AGPR overflow),
// capping residency at 4 waves/SIMD, and the grid (4096 waves) capped occupancy at 50%.
// VALUBusy 63% / Occupancy 32% => starved of waves, not of ILP. One state/wave fits in
// 64 VGPRs (forced via waves_per_eu(8,8)) and the grid now supplies 8192 waves = 32/CU.
// Tripwire: WRITE_SIZE must stay ~0.4 MB. If it balloons, the forced allocation spilled
// the statevector (R3/R5/R7 failure mode) -> revert to the 2-state kernel.
// LOCKED: reductions use plain __shfl_xor only (R8 DPP reductions diverged across graph
// replays). DPP stays confined to lane_xor<1,2> under full exec (stable since R4).

// Amplitude index i (10 bits): i = lane(6 bits, i[9:4]) * 16 + r(4 bits, i[3:0]).
// Qubit q sits at bit P = 9-q.  P>=4 -> lane qubit (lane bit P-4), P<4 -> register qubit.

typedef __attribute__((ext_vector_type(2))) float f2;

__device__ __forceinline__ f2 cswapneg(f2 v) {   // i * v = (-im, re)
    f2 r; r.x = -v.y; r.y = v.x; return r;
}

template<int LB>
__device__ __forceinline__ float lane_xor(float v) {
    if constexpr (LB == 1) {        // quad_perm [1,0,3,2]
        return __int_as_float(__builtin_amdgcn_update_dpp(
            0, __float_as_int(v), 0xB1, 0xF, 0xF, false));
    } else if constexpr (LB == 2) { // quad_perm [2,3,0,1]
        return __int_as_float(__builtin_amdgcn_update_dpp(
            0, __float_as_int(v), 0x4E, 0xF, 0xF, false));
    } else {
        return __shfl_xor(v, LB, 64);
    }
}

template<int LB>
__device__ __forceinline__ f2 lane_xor2(f2 v) {
    f2 r; r.x = lane_xor<LB>(v.x); r.y = lane_xor<LB>(v.y); return r;
}

// ---- generic complex 2x2 gate (Rot) on bit position P, single state ----
template<int P>
__device__ __forceinline__ void rot_gate(f2 (&a)[16], int lane, float4 gA, float4 gB) {
    if constexpr (P >= 4) {
        const int lb = 1 << (P - 4);
        const bool hi = (lane & lb) != 0;
        const float gdx = hi ? gB.z : gA.x, gdy = hi ? gB.w : gA.y;   // diagonal
        const float gox = hi ? gB.x : gA.z, goy = hi ? gB.y : gA.w;   // off-diagonal
#pragma unroll
        for (int r = 0; r < 16; r++) {
            f2 oa = lane_xor2<lb>(a[r]);
            f2 va = a[r];
            a[r] = gdx * va + gdy * cswapneg(va) + gox * oa + goy * cswapneg(oa);
        }
    } else {
        const int m = 1 << P;
#pragma unroll
        for (int r = 0; r < 16; r++) {
            if (!(r & m)) {
                const int r1 = r | m;
                f2 A0 = a[r], A1 = a[r1];
                f2 ia0 = cswapneg(A0), ia1 = cswapneg(A1);
                a[r]  = gA.x * A0 + gA.y * ia0 + gA.z * A1 + gA.w * ia1;
                a[r1] = gB.x * A0 + gB.y * ia0 + gB.z * A1 + gB.w * ia1;
            }
        }
    }
}

// ---- rot<9> with the PREVIOUS layer's CNOT(ctrl=reg bit0, tgt=lane bit 32) fused in ----
__device__ __forceinline__ void rot9_fused(f2 (&a)[16], int lane, float4 gA, float4 gB) {
    const bool hi = (lane & 32) != 0;
    const float gdx = hi ? gB.z : gA.x, gdy = hi ? gB.w : gA.y;
    const float gox = hi ? gB.x : gA.z, goy = hi ? gB.y : gA.w;
#pragma unroll
    for (int r = 0; r < 16; r++) {
        f2 oa; oa.x = __shfl_xor(a[r].x, 32, 64); oa.y = __shfl_xor(a[r].y, 32, 64);
        f2 va = a[r];
        if (!(r & 1)) {
            a[r] = gdx * va + gdy * cswapneg(va) + gox * oa + goy * cswapneg(oa);
        } else {   // fused CNOT: own/partner roles swapped
            a[r] = gdx * oa + gdy * cswapneg(oa) + gox * va + goy * cswapneg(va);
        }
    }
}

// ---- CNOT: control bit PC, target bit PT ----
template<int PC, int PT>
__device__ __forceinline__ void cnot_gate(f2 (&a)[16], int lane) {
    if constexpr (PC >= 4 && PT < 4) {                // lane control, register target
        const int mt = 1 << PT;
        const bool ctl = (lane & (1 << (PC - 4))) != 0;
#pragma unroll
        for (int r = 0; r < 16; r++) {
            if (!(r & mt)) {
                const int r1 = r | mt;
                f2 A0 = a[r], A1 = a[r1];
                f2 n0, n1;
                n0.x = ctl ? A1.x : A0.x;  n0.y = ctl ? A1.y : A0.y;
                n1.x = ctl ? A0.x : A1.x;  n1.y = ctl ? A0.y : A1.y;
                a[r] = n0; a[r1] = n1;
            }
        }
    } else if constexpr (PC < 4 && PT >= 4) {         // register control, lane target
        const int mc = 1 << PC, mt = 1 << (PT - 4);
#pragma unroll
        for (int r = 0; r < 16; r++) {
            if (r & mc) {
                a[r].x = __shfl_xor(a[r].x, mt, 64);
                a[r].y = __shfl_xor(a[r].y, mt, 64);
            }
        }
    } else {                                          // register-register: free rename
        const int mc = 1 << PC, mt = 1 << PT;
#pragma unroll
        for (int r = 0; r < 16; r++) {
            if ((r & mc) && !(r & mt)) {
                const int r1 = r | mt;
                f2 t = a[r]; a[r] = a[r1]; a[r1] = t;
            }
        }
    }
}

__global__ __launch_bounds__(BLOCK)
__attribute__((amdgpu_waves_per_eu(8, 8)))
void qnet_kernel(
    const float* __restrict__ x,
    const float* __restrict__ Wp,
    const float* __restrict__ bp,
    const float* __restrict__ qw,
    const float* __restrict__ Wo,
    const float* __restrict__ bo,
    float* __restrict__ out, int B)
{
    __shared__ __align__(16) float gates[NLAYERS * NQ * 8];  // per-WG Rot matrix table

    const int tid  = threadIdx.x;
    const int lane = tid & 63;
    const int s    = blockIdx.x * (BLOCK / 64) + (tid >> 6);   // one state per wave

    // ---- Rot gate table (built once per workgroup, shared by 4 waves) ----
    if (tid < NLAYERS * NQ) {
        float phi = qw[tid * 3 + 0];
        float th  = qw[tid * 3 + 1];
        float om  = qw[tid * 3 + 2];
        float sth, cth; sincosf(0.5f * th, &sth, &cth);
        float sap, cap; sincosf(0.5f * (phi + om), &sap, &cap);
        float sam, cam; sincosf(0.5f * (phi - om), &sam, &cam);
        float* g = &gates[tid * 8];
        g[0] =  cap * cth;  g[1] = -sap * cth;   // u00
        g[2] = -cam * sth;  g[3] = -sam * sth;   // u01
        g[4] =  cam * sth;  g[5] = -sam * sth;   // u10
        g[6] =  cap * cth;  g[7] =  sap * cth;   // u11
    }
    __syncthreads();
    if (s >= B) return;

    // ---- projection for this wave's state ----
    float acc[NQ];
#pragma unroll
    for (int q = 0; q < NQ; q++) acc[q] = 0.f;
    const float* xr = x + (size_t)s * D_IN;
    for (int d = lane; d < D_IN; d += 64) {
        float xv = xr[d];
#pragma unroll
        for (int q = 0; q < NQ; q++) acc[q] += xv * Wp[q * D_IN + d];
    }
#pragma unroll
    for (int q = 0; q < NQ; q++) {
#pragma unroll
        for (int o = 1; o < 64; o <<= 1) acc[q] += __shfl_xor(acc[q], o, 64);
    }
    float myc = 1.f, mys = 0.f;
    if (lane < NQ) {
        float h = tanhf(acc[lane] + bp[lane]);
        sincosf(0.5f * h, &mys, &myc);
    }

    // ---- statevector |0..0> in registers, packed (re,im) ----
    f2 a[16];
#pragma unroll
    for (int r = 0; r < 16; r++) { a[r].x = 0.f; a[r].y = 0.f; }
    if (lane == 0) a[0].x = 1.f;

    // Pull-index for the composite lane-CNOT chain: src_lane = Gray(lane)
    const int bidx = (lane ^ (lane >> 1)) << 2;

    // ---- layer 0: RY fused into Rot (per-state matrix) ----
    {
        const float* gl = &gates[0];
#define FROTQ(Q) { \
        float c0  = __shfl(myc, Q, 64); \
        float ss0 = __shfl(mys, Q, 64); \
        float4 gA = *(const float4*)(gl + Q * 8); \
        float4 gB = *(const float4*)(gl + Q * 8 + 4); \
        float4 Am, Bm; \
        Am.x = gA.x * c0 + gA.z * ss0;  Am.y = gA.y * c0 + gA.w * ss0; \
        Am.z = gA.z * c0 - gA.x * ss0;  Am.w = gA.w * c0 - gA.y * ss0; \
        Bm.x = gB.x * c0 + gB.z * ss0;  Bm.y = gB.y * c0 + gB.w * ss0; \
        Bm.z = gB.z * c0 - gB.x * ss0;  Bm.w = gB.w * c0 - gB.y * ss0; \
        rot_gate<9 - Q>(a, lane, Am, Bm); }
        FROTQ(0) FROTQ(1) FROTQ(2) FROTQ(3) FROTQ(4)
        FROTQ(5) FROTQ(6) FROTQ(7) FROTQ(8) FROTQ(9)
#undef FROTQ
        // CNOT ring (9,8)..(5,4) as one lane permutation
#pragma unroll
        for (int r = 0; r < 16; r++) {
            a[r].x = __int_as_float(__builtin_amdgcn_ds_bpermute(bidx, __float_as_int(a[r].x)));
            a[r].y = __int_as_float(__builtin_amdgcn_ds_bpermute(bidx, __float_as_int(a[r].y)));
        }
        cnot_gate<4, 3>(a, lane);
        cnot_gate<3, 2>(a, lane);
        cnot_gate<2, 1>(a, lane);
        cnot_gate<1, 0>(a, lane);
        // cnot<0,9> fused into next layer's rot<9>
    }

    // ---- layers 1..3 (first gate consumes previous layer's trailing cnot<0,9>) ----
    for (int l = 1; l < NLAYERS; l++) {
        const float* gl = &gates[l * NQ * 8];
        {   float4 gA = *(const float4*)(gl);
            float4 gB = *(const float4*)(gl + 4);
            rot9_fused(a, lane, gA, gB); }
#define ROTQ(Q) { float4 gA = *(const float4*)(gl + Q * 8); \
                  float4 gB = *(const float4*)(gl + Q * 8 + 4); \
                  rot_gate<9 - Q>(a, lane, gA, gB); }
        ROTQ(1) ROTQ(2) ROTQ(3) ROTQ(4)
        ROTQ(5) ROTQ(6) ROTQ(7) ROTQ(8) ROTQ(9)
#undef ROTQ
#pragma unroll
        for (int r = 0; r < 16; r++) {
            a[r].x = __int_as_float(__builtin_amdgcn_ds_bpermute(bidx, __float_as_int(a[r].x)));
            a[r].y = __int_as_float(__builtin_amdgcn_ds_bpermute(bidx, __float_as_int(a[r].y)));
        }
        cnot_gate<4, 3>(a, lane);
        cnot_gate<3, 2>(a, lane);
        cnot_gate<2, 1>(a, lane);
        cnot_gate<1, 0>(a, lane);
    }
    // layer 3's trailing cnot<0,9> applied for real (measurement follows)
    cnot_gate<0, 9>(a, lane);

    // ---- measurement: Z expectation per qubit ----
    float S = 0.f, z3 = 0.f, z2 = 0.f, z1 = 0.f, z0 = 0.f;
#pragma unroll
    for (int r = 0; r < 16; r++) {
        float pa = a[r].x * a[r].x + a[r].y * a[r].y;
        S += pa;
        z3 += (r & 8) ? -pa : pa;
        z2 += (r & 4) ? -pa : pa;
        z1 += (r & 2) ? -pa : pa;
        z0 += (r & 1) ? -pa : pa;
    }
    float zq[NQ];
    zq[6] = z3; zq[7] = z2; zq[8] = z1; zq[9] = z0;
#pragma unroll
    for (int q = 0; q < 6; q++) {                      // lane qubits: lane bit 5-q
        zq[q] = ((lane >> (5 - q)) & 1) ? -S : S;
    }
#pragma unroll
    for (int q = 0; q < NQ; q++) {
#pragma unroll
        for (int o = 1; o < 64; o <<= 1) {
            zq[q] += __shfl_xor(zq[q], o, 64);
        }
    }

    // ---- output projection: out = zq @ Wo^T + bo ----
    if (lane < NQ) {
        const float* wrow = Wo + lane * NQ;
        float o0 = bo[lane];
#pragma unroll
        for (int q = 0; q < NQ; q++) o0 += zq[q] * wrow[q];
        out[(size_t)s * NQ + lane] = o0;
    }
}

extern "C" void kernel_launch(void* const* d_in, const int* in_sizes, int n_in,
                              void* d_out, int out_size, void* d_ws, size_t ws_size,
                              hipStream_t stream) {
    const float* x  = (const float*)d_in[0];
    const float* Wp = (const float*)d_in[1];
    const float* bp = (const float*)d_in[2];
    const float* qw = (const float*)d_in[3];
    const float* Wo = (const float*)d_in[4];
    const float* bo = (const float*)d_in[5];
    float* out = (float*)d_out;

    const int B = in_sizes[0] / D_IN;                  // 8192 states, one per wave
    const int spb = BLOCK / 64;                        // states per block (4)
    const int blocks = (B + spb - 1) / spb;
    hipLaunchKernelGGL(qnet_kernel, dim3(blocks), dim3(BLOCK), 0, stream,
                       x, Wp, bp, qw, Wo, bo, out, B);
}

// Round 2
// 162.014 us; speedup vs baseline: 1.0317x; 1.0303x over previous
//
#include <hip/hip_runtime.h>

#define NQ      10
#define NLAYERS 4
#define D_IN    784
#define BLOCK   256            // 4 waves per workgroup, ONE state per wave.
// R14: waves_per_eu(8,8) in R13 forced VGPR_Count=32 -> statevector spilled to scratch
// (WRITE_SIZE 0.4MB -> 27MB tripwire fired); occupancy 56% but dur flat at 114us.
// Lesson: >=50% occupancy is NOT the lever; spill + DS-pipe pressure are.
//   (a) waves_per_eu(4,8): 128-reg budget, one state fits (~80 regs), no spill.
//   (b) P=9/P=8 lane-gates now use v_permlane32/16_swap_b32 (VALU pipe) pair-wise
//       instead of 2x16 ds-shuffles each: removes 256 of ~780 DS ops per state and
//       makes gate coefficients lane-uniform (drops hi/lo selects).
//   (c) projection loads vectorized float4 (134 -> ~34 VMEM inst/wave).
// Tripwire: WRITE_SIZE must stay ~0.4 MB. If it balloons, registers spilled -> revert.
// LOCKED: reductions use plain __shfl_xor only (R8 DPP reductions diverged across graph
// replays). DPP stays confined to lane_xor<1,2> under full exec (stable since R4).

// Amplitude index i (10 bits): i = lane(6 bits, i[9:4]) * 16 + r(4 bits, i[3:0]).
// Qubit q sits at bit P = 9-q.  P>=4 -> lane qubit (lane bit P-4), P<4 -> register qubit.

typedef __attribute__((ext_vector_type(2))) float f2;

__device__ __forceinline__ f2 cswapneg(f2 v) {   // i * v = (-im, re)
    f2 r; r.x = -v.y; r.y = v.x; return r;
}

template<int LB>
__device__ __forceinline__ float lane_xor(float v) {
    if constexpr (LB == 1) {        // quad_perm [1,0,3,2]
        return __int_as_float(__builtin_amdgcn_update_dpp(
            0, __float_as_int(v), 0xB1, 0xF, 0xF, false));
    } else if constexpr (LB == 2) { // quad_perm [2,3,0,1]
        return __int_as_float(__builtin_amdgcn_update_dpp(
            0, __float_as_int(v), 0x4E, 0xF, 0xF, false));
    } else {
        return __shfl_xor(v, LB, 64);
    }
}

template<int LB>
__device__ __forceinline__ f2 lane_xor2(f2 v) {
    f2 r; r.x = lane_xor<LB>(v.x); r.y = lane_xor<LB>(v.y); return r;
}

// ---- permlane pair swap: after swap, every lane holds (u = bit=0 elem, v = bit=1 elem)
// of one amplitude-pair; lanes in the "D half" process amp d, others amp s.  VALU pipe.
template<int HALF>   // HALF = 32 (lane bit 32, v_permlane32_swap) or 16 (lane bit 16)
__device__ __forceinline__ void plswap(f2 &d, f2 &s) {
    if constexpr (HALF == 32) {
        auto rx = __builtin_amdgcn_permlane32_swap(__float_as_int(d.x), __float_as_int(s.x), false, false);
        auto ry = __builtin_amdgcn_permlane32_swap(__float_as_int(d.y), __float_as_int(s.y), false, false);
        d.x = __int_as_float(rx[0]); s.x = __int_as_float(rx[1]);
        d.y = __int_as_float(ry[0]); s.y = __int_as_float(ry[1]);
    } else {
        auto rx = __builtin_amdgcn_permlane16_swap(__float_as_int(d.x), __float_as_int(s.x), false, false);
        auto ry = __builtin_amdgcn_permlane16_swap(__float_as_int(d.y), __float_as_int(s.y), false, false);
        d.x = __int_as_float(rx[0]); s.x = __int_as_float(rx[1]);
        d.y = __int_as_float(ry[0]); s.y = __int_as_float(ry[1]);
    }
}

// ---- Rot on lane bit HALF via permlane pair-processing: gate coefs lane-UNIFORM ----
template<int HALF>
__device__ __forceinline__ void rot_gate_pl(f2 (&a)[16], float4 gA, float4 gB) {
#pragma unroll
    for (int r = 0; r < 16; r += 2) {
        f2 u = a[r], v = a[r + 1];
        plswap<HALF>(u, v);                      // u = low elem, v = high elem (all lanes)
        f2 iu = cswapneg(u), iv = cswapneg(v);
        f2 nu = gA.x * u + gA.y * iu + gA.z * v + gA.w * iv;
        f2 nv = gB.x * u + gB.y * iu + gB.z * v + gB.w * iv;
        plswap<HALF>(nu, nv);                    // scatter results back
        a[r] = nu; a[r + 1] = nv;
    }
}

// ---- rot<9> (lane bit 32) with PREVIOUS layer's CNOT(ctrl=reg bit0, tgt=bit32) fused.
// Pairs (even r, odd r): lanes<32 process even amp (normal), lanes>=32 odd amp (roles
// swapped by the consumed CNOT) -> per-half coefficient select, hoisted out of the loop.
__device__ __forceinline__ void rot9_fused_pl(f2 (&a)[16], int lane, float4 gA, float4 gB) {
    const bool hi = (lane & 32) != 0;
    const float cux = hi ? gA.z : gA.x, cuy = hi ? gA.w : gA.y;
    const float cvx = hi ? gA.x : gA.z, cvy = hi ? gA.y : gA.w;
    const float dux = hi ? gB.z : gB.x, duy = hi ? gB.w : gB.y;
    const float dvx = hi ? gB.x : gB.z, dvy = hi ? gB.y : gB.w;
#pragma unroll
    for (int r = 0; r < 16; r += 2) {
        f2 u = a[r], v = a[r + 1];
        plswap<32>(u, v);
        f2 iu = cswapneg(u), iv = cswapneg(v);
        f2 nu = cux * u + cuy * iu + cvx * v + cvy * iv;
        f2 nv = dux * u + duy * iu + dvx * v + dvy * iv;
        plswap<32>(nu, nv);
        a[r] = nu; a[r + 1] = nv;
    }
}

// ---- generic complex 2x2 gate (Rot) on bit position P (P<=7 lane via DS, P<4 register) ----
template<int P>
__device__ __forceinline__ void rot_gate(f2 (&a)[16], int lane, float4 gA, float4 gB) {
    if constexpr (P >= 4) {
        const int lb = 1 << (P - 4);
        const bool hi = (lane & lb) != 0;
        const float gdx = hi ? gB.z : gA.x, gdy = hi ? gB.w : gA.y;   // diagonal
        const float gox = hi ? gB.x : gA.z, goy = hi ? gB.y : gA.w;   // off-diagonal
#pragma unroll
        for (int r = 0; r < 16; r++) {
            f2 oa = lane_xor2<lb>(a[r]);
            f2 va = a[r];
            a[r] = gdx * va + gdy * cswapneg(va) + gox * oa + goy * cswapneg(oa);
        }
    } else {
        const int m = 1 << P;
#pragma unroll
        for (int r = 0; r < 16; r++) {
            if (!(r & m)) {
                const int r1 = r | m;
                f2 A0 = a[r], A1 = a[r1];
                f2 ia0 = cswapneg(A0), ia1 = cswapneg(A1);
                a[r]  = gA.x * A0 + gA.y * ia0 + gA.z * A1 + gA.w * ia1;
                a[r1] = gB.x * A0 + gB.y * ia0 + gB.z * A1 + gB.w * ia1;
            }
        }
    }
}

// ---- CNOT: control bit PC, target bit PT ----
template<int PC, int PT>
__device__ __forceinline__ void cnot_gate(f2 (&a)[16], int lane) {
    if constexpr (PC >= 4 && PT < 4) {                // lane control, register target
        const int mt = 1 << PT;
        const bool ctl = (lane & (1 << (PC - 4))) != 0;
#pragma unroll
        for (int r = 0; r < 16; r++) {
            if (!(r & mt)) {
                const int r1 = r | mt;
                f2 A0 = a[r], A1 = a[r1];
                f2 n0, n1;
                n0.x = ctl ? A1.x : A0.x;  n0.y = ctl ? A1.y : A0.y;
                n1.x = ctl ? A0.x : A1.x;  n1.y = ctl ? A0.y : A1.y;
                a[r] = n0; a[r1] = n1;
            }
        }
    } else if constexpr (PC < 4 && PT >= 4) {         // register control, lane target
        const int mc = 1 << PC, mt = 1 << (PT - 4);
#pragma unroll
        for (int r = 0; r < 16; r++) {
            if (r & mc) {
                a[r].x = __shfl_xor(a[r].x, mt, 64);
                a[r].y = __shfl_xor(a[r].y, mt, 64);
            }
        }
    } else {                                          // register-register: free rename
        const int mc = 1 << PC, mt = 1 << PT;
#pragma unroll
        for (int r = 0; r < 16; r++) {
            if ((r & mc) && !(r & mt)) {
                const int r1 = r | mt;
                f2 t = a[r]; a[r] = a[r1]; a[r1] = t;
            }
        }
    }
}

__global__ __launch_bounds__(BLOCK)
__attribute__((amdgpu_waves_per_eu(4, 8)))
void qnet_kernel(
    const float* __restrict__ x,
    const float* __restrict__ Wp,
    const float* __restrict__ bp,
    const float* __restrict__ qw,
    const float* __restrict__ Wo,
    const float* __restrict__ bo,
    float* __restrict__ out, int B)
{
    __shared__ __align__(16) float gates[NLAYERS * NQ * 8];  // per-WG Rot matrix table

    const int tid  = threadIdx.x;
    const int lane = tid & 63;
    const int s    = blockIdx.x * (BLOCK / 64) + (tid >> 6);   // one state per wave

    // ---- Rot gate table (built once per workgroup, shared by 4 waves) ----
    if (tid < NLAYERS * NQ) {
        float phi = qw[tid * 3 + 0];
        float th  = qw[tid * 3 + 1];
        float om  = qw[tid * 3 + 2];
        float sth, cth; sincosf(0.5f * th, &sth, &cth);
        float sap, cap; sincosf(0.5f * (phi + om), &sap, &cap);
        float sam, cam; sincosf(0.5f * (phi - om), &sam, &cam);
        float* g = &gates[tid * 8];
        g[0] =  cap * cth;  g[1] = -sap * cth;   // u00
        g[2] = -cam * sth;  g[3] = -sam * sth;   // u01
        g[4] =  cam * sth;  g[5] = -sam * sth;   // u10
        g[6] =  cap * cth;  g[7] =  sap * cth;   // u11
    }
    __syncthreads();
    if (s >= B) return;

    // ---- projection for this wave's state (float4 vectorized: 784 = 3*256 + 16) ----
    float acc[NQ];
#pragma unroll
    for (int q = 0; q < NQ; q++) acc[q] = 0.f;
    const float* xr = x + (size_t)s * D_IN;
#pragma unroll
    for (int it = 0; it < 3; it++) {
        const int d = (it * 64 + lane) * 4;
        float4 xv = *(const float4*)(xr + d);
#pragma unroll
        for (int q = 0; q < NQ; q++) {
            float4 wv = *(const float4*)(Wp + q * D_IN + d);
            acc[q] += xv.x * wv.x + xv.y * wv.y + xv.z * wv.z + xv.w * wv.w;
        }
    }
    if (lane < 4) {                                    // tail 768..783
        const int d = (192 + lane) * 4;
        float4 xv = *(const float4*)(xr + d);
#pragma unroll
        for (int q = 0; q < NQ; q++) {
            float4 wv = *(const float4*)(Wp + q * D_IN + d);
            acc[q] += xv.x * wv.x + xv.y * wv.y + xv.z * wv.z + xv.w * wv.w;
        }
    }
#pragma unroll
    for (int q = 0; q < NQ; q++) {
#pragma unroll
        for (int o = 1; o < 64; o <<= 1) acc[q] += __shfl_xor(acc[q], o, 64);
    }
    float myc = 1.f, mys = 0.f;
    if (lane < NQ) {
        float h = tanhf(acc[lane] + bp[lane]);
        sincosf(0.5f * h, &mys, &myc);
    }

    // ---- statevector |0..0> in registers, packed (re,im) ----
    f2 a[16];
#pragma unroll
    for (int r = 0; r < 16; r++) { a[r].x = 0.f; a[r].y = 0.f; }
    if (lane == 0) a[0].x = 1.f;

    // Pull-index for the composite lane-CNOT chain: src_lane = Gray(lane)
    const int bidx = (lane ^ (lane >> 1)) << 2;

    // ---- layer 0: RY fused into Rot (per-state matrix, wave-uniform coefs) ----
    {
        const float* gl = &gates[0];
#define MKMAT(Q) \
        float c0  = __shfl(myc, Q, 64); \
        float ss0 = __shfl(mys, Q, 64); \
        float4 gA = *(const float4*)(gl + Q * 8); \
        float4 gB = *(const float4*)(gl + Q * 8 + 4); \
        float4 Am, Bm; \
        Am.x = gA.x * c0 + gA.z * ss0;  Am.y = gA.y * c0 + gA.w * ss0; \
        Am.z = gA.z * c0 - gA.x * ss0;  Am.w = gA.w * c0 - gA.y * ss0; \
        Bm.x = gB.x * c0 + gB.z * ss0;  Bm.y = gB.y * c0 + gB.w * ss0; \
        Bm.z = gB.z * c0 - gB.x * ss0;  Bm.w = gB.w * c0 - gB.y * ss0;
        { MKMAT(0); rot_gate_pl<32>(a, Am, Bm); }      // P=9: permlane pair gate
        { MKMAT(1); rot_gate_pl<16>(a, Am, Bm); }      // P=8: permlane pair gate
        { MKMAT(2); rot_gate<7>(a, lane, Am, Bm); }
        { MKMAT(3); rot_gate<6>(a, lane, Am, Bm); }
        { MKMAT(4); rot_gate<5>(a, lane, Am, Bm); }
        { MKMAT(5); rot_gate<4>(a, lane, Am, Bm); }
        { MKMAT(6); rot_gate<3>(a, lane, Am, Bm); }
        { MKMAT(7); rot_gate<2>(a, lane, Am, Bm); }
        { MKMAT(8); rot_gate<1>(a, lane, Am, Bm); }
        { MKMAT(9); rot_gate<0>(a, lane, Am, Bm); }
#undef MKMAT
        // CNOT ring (9,8)..(5,4) as one lane permutation
#pragma unroll
        for (int r = 0; r < 16; r++) {
            a[r].x = __int_as_float(__builtin_amdgcn_ds_bpermute(bidx, __float_as_int(a[r].x)));
            a[r].y = __int_as_float(__builtin_amdgcn_ds_bpermute(bidx, __float_as_int(a[r].y)));
        }
        cnot_gate<4, 3>(a, lane);
        cnot_gate<3, 2>(a, lane);
        cnot_gate<2, 1>(a, lane);
        cnot_gate<1, 0>(a, lane);
        // cnot<0,9> fused into next layer's rot<9>
    }

    // ---- layers 1..3 (first gate consumes previous layer's trailing cnot<0,9>) ----
    for (int l = 1; l < NLAYERS; l++) {
        const float* gl = &gates[l * NQ * 8];
        {   float4 gA = *(const float4*)(gl);
            float4 gB = *(const float4*)(gl + 4);
            rot9_fused_pl(a, lane, gA, gB); }
        {   float4 gA = *(const float4*)(gl + 8);
            float4 gB = *(const float4*)(gl + 12);
            rot_gate_pl<16>(a, gA, gB); }              // P=8: permlane pair gate
#define ROTQ(Q) { float4 gA = *(const float4*)(gl + Q * 8); \
                  float4 gB = *(const float4*)(gl + Q * 8 + 4); \
                  rot_gate<9 - Q>(a, lane, gA, gB); }
        ROTQ(2) ROTQ(3) ROTQ(4)
        ROTQ(5) ROTQ(6) ROTQ(7) ROTQ(8) ROTQ(9)
#undef ROTQ
#pragma unroll
        for (int r = 0; r < 16; r++) {
            a[r].x = __int_as_float(__builtin_amdgcn_ds_bpermute(bidx, __float_as_int(a[r].x)));
            a[r].y = __int_as_float(__builtin_amdgcn_ds_bpermute(bidx, __float_as_int(a[r].y)));
        }
        cnot_gate<4, 3>(a, lane);
        cnot_gate<3, 2>(a, lane);
        cnot_gate<2, 1>(a, lane);
        cnot_gate<1, 0>(a, lane);
    }
    // layer 3's trailing cnot<0,9> applied for real (measurement follows)
    cnot_gate<0, 9>(a, lane);

    // ---- measurement: Z expectation per qubit ----
    float S = 0.f, z3 = 0.f, z2 = 0.f, z1 = 0.f, z0 = 0.f;
#pragma unroll
    for (int r = 0; r < 16; r++) {
        float pa = a[r].x * a[r].x + a[r].y * a[r].y;
        S += pa;
        z3 += (r & 8) ? -pa : pa;
        z2 += (r & 4) ? -pa : pa;
        z1 += (r & 2) ? -pa : pa;
        z0 += (r & 1) ? -pa : pa;
    }
    float zq[NQ];
    zq[6] = z3; zq[7] = z2; zq[8] = z1; zq[9] = z0;
#pragma unroll
    for (int q = 0; q < 6; q++) {                      // lane qubits: lane bit 5-q
        zq[q] = ((lane >> (5 - q)) & 1) ? -S : S;
    }
#pragma unroll
    for (int q = 0; q < NQ; q++) {
#pragma unroll
        for (int o = 1; o < 64; o <<= 1) {
            zq[q] += __shfl_xor(zq[q], o, 64);
        }
    }

    // ---- output projection: out = zq @ Wo^T + bo ----
    if (lane < NQ) {
        const float* wrow = Wo + lane * NQ;
        float o0 = bo[lane];
#pragma unroll
        for (int q = 0; q < NQ; q++) o0 += zq[q] * wrow[q];
        out[(size_t)s * NQ + lane] = o0;
    }
}

extern "C" void kernel_launch(void* const* d_in, const int* in_sizes, int n_in,
                              void* d_out, int out_size, void* d_ws, size_t ws_size,
                              hipStream_t stream) {
    const float* x  = (const float*)d_in[0];
    const float* Wp = (const float*)d_in[1];
    const float* bp = (const float*)d_in[2];
    const float* qw = (const float*)d_in[3];
    const float* Wo = (const float*)d_in[4];
    const float* bo = (const float*)d_in[5];
    float* out = (float*)d_out;

    const int B = in_sizes[0] / D_IN;                  // 8192 states, one per wave
    const int spb = BLOCK / 64;                        // states per block (4)
    const int blocks = (B + spb - 1) / spb;
    hipLaunchKernelGGL(qnet_kernel, dim3(blocks), dim3(BLOCK), 0, stream,
                       x, Wp, bp, qw, Wo, bo, out, B);
}

// Round 3
// 149.323 us; speedup vs baseline: 1.1194x; 1.0850x over previous
//
#include <hip/hip_runtime.h>

#define NQ      10
#define NLAYERS 4
#define D_IN    784
#define BLOCK   256            // 4 waves per workgroup, TWO states per wave (pk-packed).
// R15: state-packed components. R14 analysis: 108us x 76% VALUBusy = ~12.3k VALU inst/wave
// vs ~4-5k algorithmic ideal -> codegen overhead, prime suspect cswapneg (cross-component
// swap+neg defeats v_pk_fma matching). New layout: re[16],im[16] f2 arrays with components
// = (stateA, stateB). All gate math is component-wise f2 -> guaranteed v_pk_* lowering,
// zero component swaps. Per-wave fixed costs (MKMAT etc) amortize over 2 states; layer-0
// per-state matrices pack naturally as f2 coefficients.
// Tripwire: WRITE_SIZE must stay ~0.3 MB. If MBs appeared, 128-reg cap spilled -> revert
// to R14 or relax to waves_per_eu(3,8).
// LOCKED: reductions use plain __shfl_xor only (R8 DPP reductions diverged across graph
// replays). DPP stays confined to lane_xor<1,2> under full exec (stable since R4).

// Amplitude index i (10 bits): i = lane(6 bits, i[9:4]) * 16 + r(4 bits, i[3:0]).
// Qubit q sits at bit P = 9-q.  P>=4 -> lane qubit (lane bit P-4), P<4 -> register qubit.

typedef __attribute__((ext_vector_type(2))) float f2;

__device__ __forceinline__ f2 sp(float v) { f2 r; r.x = v; r.y = v; return r; }

struct G2 { f2 Ax, Ay, Az, Aw, Bx, By, Bz, Bw; };   // u00=(Ax,Ay) u01=(Az,Aw) u10=(Bx,By) u11=(Bz,Bw)

template<int LB>
__device__ __forceinline__ float lane_xor(float v) {
    if constexpr (LB == 1) {        // quad_perm [1,0,3,2]
        return __int_as_float(__builtin_amdgcn_update_dpp(
            0, __float_as_int(v), 0xB1, 0xF, 0xF, false));
    } else if constexpr (LB == 2) { // quad_perm [2,3,0,1]
        return __int_as_float(__builtin_amdgcn_update_dpp(
            0, __float_as_int(v), 0x4E, 0xF, 0xF, false));
    } else {
        return __shfl_xor(v, LB, 64);
    }
}

template<int LB>
__device__ __forceinline__ f2 lane_xor2(f2 v) {
    f2 r; r.x = lane_xor<LB>(v.x); r.y = lane_xor<LB>(v.y); return r;
}

// ---- permlane pair swap (VALU pipe): exchanges lane-halves between two registers ----
template<int HALF>   // HALF = 32 (v_permlane32_swap) or 16 (v_permlane16_swap)
__device__ __forceinline__ void plswap(f2 &d, f2 &s) {
    if constexpr (HALF == 32) {
        auto rx = __builtin_amdgcn_permlane32_swap(__float_as_int(d.x), __float_as_int(s.x), false, false);
        auto ry = __builtin_amdgcn_permlane32_swap(__float_as_int(d.y), __float_as_int(s.y), false, false);
        d.x = __int_as_float(rx[0]); s.x = __int_as_float(rx[1]);
        d.y = __int_as_float(ry[0]); s.y = __int_as_float(ry[1]);
    } else {
        auto rx = __builtin_amdgcn_permlane16_swap(__float_as_int(d.x), __float_as_int(s.x), false, false);
        auto ry = __builtin_amdgcn_permlane16_swap(__float_as_int(d.y), __float_as_int(s.y), false, false);
        d.x = __int_as_float(rx[0]); s.x = __int_as_float(rx[1]);
        d.y = __int_as_float(ry[0]); s.y = __int_as_float(ry[1]);
    }
}

// ---- Rot on lane bit HALF via permlane pair-processing (coefs uniform across lanes) ----
template<int HALF>
__device__ __forceinline__ void rot_gate_pl_c(f2 (&re)[16], f2 (&im)[16], const G2& g) {
#pragma unroll
    for (int r = 0; r < 16; r += 2) {
        f2 ur = re[r], vr = re[r + 1], ui = im[r], vi = im[r + 1];
        plswap<HALF>(ur, vr); plswap<HALF>(ui, vi);
        // (ur,ui) = bit=0 amp, (vr,vi) = bit=1 amp, in every lane
        f2 nur = g.Ax*ur - g.Ay*ui + g.Az*vr - g.Aw*vi;
        f2 nui = g.Ax*ui + g.Ay*ur + g.Az*vi + g.Aw*vr;
        f2 nvr = g.Bx*ur - g.By*ui + g.Bz*vr - g.Bw*vi;
        f2 nvi = g.Bx*ui + g.By*ur + g.Bz*vi + g.Bw*vr;
        plswap<HALF>(nur, nvr); plswap<HALF>(nui, nvi);
        re[r] = nur; re[r + 1] = nvr; im[r] = nui; im[r + 1] = nvi;
    }
}

// ---- rot<9> with PREVIOUS layer's CNOT(ctrl=reg bit0, tgt=lane bit32) fused in ----
__device__ __forceinline__ void rot9_fused_c(f2 (&re)[16], f2 (&im)[16], int lane, const G2& g) {
    const bool hi = (lane & 32) != 0;
    // lanes<32 process even r (normal roles); lanes>=32 process odd r (CNOT-swapped roles)
    const f2 cAx = hi ? g.Az : g.Ax, cAy = hi ? g.Aw : g.Ay;   // coef on u
    const f2 cAz = hi ? g.Ax : g.Az, cAw = hi ? g.Ay : g.Aw;   // coef on v
    const f2 cBx = hi ? g.Bz : g.Bx, cBy = hi ? g.Bw : g.By;
    const f2 cBz = hi ? g.Bx : g.Bz, cBw = hi ? g.By : g.Bw;
#pragma unroll
    for (int r = 0; r < 16; r += 2) {
        f2 ur = re[r], vr = re[r + 1], ui = im[r], vi = im[r + 1];
        plswap<32>(ur, vr); plswap<32>(ui, vi);
        f2 nur = cAx*ur - cAy*ui + cAz*vr - cAw*vi;
        f2 nui = cAx*ui + cAy*ur + cAz*vi + cAw*vr;
        f2 nvr = cBx*ur - cBy*ui + cBz*vr - cBw*vi;
        f2 nvi = cBx*ui + cBy*ur + cBz*vi + cBw*vr;
        plswap<32>(nur, nvr); plswap<32>(nui, nvi);
        re[r] = nur; re[r + 1] = nvr; im[r] = nui; im[r + 1] = nvi;
    }
}

// ---- generic Rot on bit P (P=7..4 lane via DS/DPP, P<4 register pairs) ----
template<int P>
__device__ __forceinline__ void rot_gate_c(f2 (&re)[16], f2 (&im)[16], int lane, const G2& g) {
    if constexpr (P >= 4) {
        const int lb = 1 << (P - 4);
        const bool hi = (lane & lb) != 0;
        const f2 gdx = hi ? g.Bz : g.Ax, gdy = hi ? g.Bw : g.Ay;   // diagonal coef
        const f2 gox = hi ? g.Bx : g.Az, goy = hi ? g.By : g.Aw;   // off-diagonal coef
#pragma unroll
        for (int r = 0; r < 16; r++) {
            f2 ore = lane_xor2<lb>(re[r]);
            f2 oim = lane_xor2<lb>(im[r]);
            f2 vr = re[r], vi = im[r];
            re[r] = gdx*vr - gdy*vi + gox*ore - goy*oim;
            im[r] = gdx*vi + gdy*vr + gox*oim + goy*ore;
        }
    } else {
        const int m = 1 << P;
#pragma unroll
        for (int r = 0; r < 16; r++) {
            if (!(r & m)) {
                const int r1 = r | m;
                f2 r0r = re[r], r0i = im[r], r1r = re[r1], r1i = im[r1];
                re[r]  = g.Ax*r0r - g.Ay*r0i + g.Az*r1r - g.Aw*r1i;
                im[r]  = g.Ax*r0i + g.Ay*r0r + g.Az*r1i + g.Aw*r1r;
                re[r1] = g.Bx*r0r - g.By*r0i + g.Bz*r1r - g.Bw*r1i;
                im[r1] = g.Bx*r0i + g.By*r0r + g.Bz*r1i + g.Bw*r1r;
            }
        }
    }
}

// ---- CNOT: control bit PC, target bit PT ----
template<int PC, int PT>
__device__ __forceinline__ void cnot_gate_c(f2 (&re)[16], f2 (&im)[16], int lane) {
    if constexpr (PC >= 4 && PT < 4) {                // lane control, register target
        const int mt = 1 << PT;
        const bool ctl = (lane & (1 << (PC - 4))) != 0;
#pragma unroll
        for (int r = 0; r < 16; r++) {
            if (!(r & mt)) {
                const int r1 = r | mt;
                f2 A0 = re[r], A1 = re[r1], B0 = im[r], B1 = im[r1];
                f2 n0, n1, m0, m1;
                n0.x = ctl ? A1.x : A0.x;  n0.y = ctl ? A1.y : A0.y;
                n1.x = ctl ? A0.x : A1.x;  n1.y = ctl ? A0.y : A1.y;
                m0.x = ctl ? B1.x : B0.x;  m0.y = ctl ? B1.y : B0.y;
                m1.x = ctl ? B0.x : B1.x;  m1.y = ctl ? B0.y : B1.y;
                re[r] = n0; re[r1] = n1; im[r] = m0; im[r1] = m1;
            }
        }
    } else if constexpr (PC < 4 && PT >= 4) {         // register control, lane target
        const int mc = 1 << PC, mt = 1 << (PT - 4);
#pragma unroll
        for (int r = 0; r < 16; r++) {
            if (r & mc) {
                re[r].x = __shfl_xor(re[r].x, mt, 64);
                re[r].y = __shfl_xor(re[r].y, mt, 64);
                im[r].x = __shfl_xor(im[r].x, mt, 64);
                im[r].y = __shfl_xor(im[r].y, mt, 64);
            }
        }
    } else {                                          // register-register: free rename
        const int mc = 1 << PC, mt = 1 << PT;
#pragma unroll
        for (int r = 0; r < 16; r++) {
            if ((r & mc) && !(r & mt)) {
                const int r1 = r | mt;
                f2 t = re[r]; re[r] = re[r1]; re[r1] = t;
                f2 u = im[r]; im[r] = im[r1]; im[r1] = u;
            }
        }
    }
}

__device__ __forceinline__ G2 load_g(const float* gl, int q) {
    float4 gA = *(const float4*)(gl + q * 8);
    float4 gB = *(const float4*)(gl + q * 8 + 4);
    G2 g;
    g.Ax = sp(gA.x); g.Ay = sp(gA.y); g.Az = sp(gA.z); g.Aw = sp(gA.w);
    g.Bx = sp(gB.x); g.By = sp(gB.y); g.Bz = sp(gB.z); g.Bw = sp(gB.w);
    return g;
}

__global__ __launch_bounds__(BLOCK)
__attribute__((amdgpu_waves_per_eu(4, 8)))
void qnet_kernel(
    const float* __restrict__ x,
    const float* __restrict__ Wp,
    const float* __restrict__ bp,
    const float* __restrict__ qw,
    const float* __restrict__ Wo,
    const float* __restrict__ bo,
    float* __restrict__ out, int B)
{
    __shared__ __align__(16) float gates[NLAYERS * NQ * 8];  // per-WG Rot matrix table

    const int tid  = threadIdx.x;
    const int lane = tid & 63;
    const int s0   = (blockIdx.x * (BLOCK / 64) + (tid >> 6)) * 2;  // two states per wave
    const int s1   = s0 + 1;

    // ---- Rot gate table (built once per workgroup, shared by 4 waves / 8 states) ----
    if (tid < NLAYERS * NQ) {
        float phi = qw[tid * 3 + 0];
        float th  = qw[tid * 3 + 1];
        float om  = qw[tid * 3 + 2];
        float sth, cth; sincosf(0.5f * th, &sth, &cth);
        float sap, cap; sincosf(0.5f * (phi + om), &sap, &cap);
        float sam, cam; sincosf(0.5f * (phi - om), &sam, &cam);
        float* g = &gates[tid * 8];
        g[0] =  cap * cth;  g[1] = -sap * cth;   // u00
        g[2] = -cam * sth;  g[3] = -sam * sth;   // u01
        g[4] =  cam * sth;  g[5] = -sam * sth;   // u10
        g[6] =  cap * cth;  g[7] =  sap * cth;   // u11
    }
    __syncthreads();
    if (s0 >= B) return;

    // ---- projection for both states (Wp load shared; float4: 784 = 3*256 + 16) ----
    float acc0[NQ], acc1[NQ];
#pragma unroll
    for (int q = 0; q < NQ; q++) { acc0[q] = 0.f; acc1[q] = 0.f; }
    const float* xr0 = x + (size_t)s0 * D_IN;
    const float* xr1 = x + (size_t)s1 * D_IN;
#pragma unroll
    for (int it = 0; it < 3; it++) {
        const int d = (it * 64 + lane) * 4;
        float4 xv0 = *(const float4*)(xr0 + d);
        float4 xv1 = *(const float4*)(xr1 + d);
#pragma unroll
        for (int q = 0; q < NQ; q++) {
            float4 wv = *(const float4*)(Wp + q * D_IN + d);
            acc0[q] += xv0.x * wv.x + xv0.y * wv.y + xv0.z * wv.z + xv0.w * wv.w;
            acc1[q] += xv1.x * wv.x + xv1.y * wv.y + xv1.z * wv.z + xv1.w * wv.w;
        }
    }
    if (lane < 4) {                                    // tail 768..783
        const int d = (192 + lane) * 4;
        float4 xv0 = *(const float4*)(xr0 + d);
        float4 xv1 = *(const float4*)(xr1 + d);
#pragma unroll
        for (int q = 0; q < NQ; q++) {
            float4 wv = *(const float4*)(Wp + q * D_IN + d);
            acc0[q] += xv0.x * wv.x + xv0.y * wv.y + xv0.z * wv.z + xv0.w * wv.w;
            acc1[q] += xv1.x * wv.x + xv1.y * wv.y + xv1.z * wv.z + xv1.w * wv.w;
        }
    }
#pragma unroll
    for (int q = 0; q < NQ; q++) {
#pragma unroll
        for (int o = 1; o < 64; o <<= 1) {
            acc0[q] += __shfl_xor(acc0[q], o, 64);
            acc1[q] += __shfl_xor(acc1[q], o, 64);
        }
    }
    float myc0 = 1.f, mys0 = 0.f, myc1 = 1.f, mys1 = 0.f;
    if (lane < NQ) {
        float h0 = tanhf(acc0[lane] + bp[lane]);
        float h1 = tanhf(acc1[lane] + bp[lane]);
        sincosf(0.5f * h0, &mys0, &myc0);
        sincosf(0.5f * h1, &mys1, &myc1);
    }

    // ---- statevectors |0..0>: components = (state A, state B) ----
    f2 re[16], im[16];
#pragma unroll
    for (int r = 0; r < 16; r++) { re[r] = sp(0.f); im[r] = sp(0.f); }
    if (lane == 0) { re[0].x = 1.f; re[0].y = 1.f; }

    // Pull-index for the composite lane-CNOT chain: src_lane = Gray(lane)
    const int bidx = (lane ^ (lane >> 1)) << 2;

    // ---- layer 0: RY fused into Rot (per-state matrices packed as f2 components) ----
    {
        const float* gl = &gates[0];
#define FROTQ(Q, GATECALL) { \
        f2 cc, ss; \
        cc.x = __shfl(myc0, Q, 64); cc.y = __shfl(myc1, Q, 64); \
        ss.x = __shfl(mys0, Q, 64); ss.y = __shfl(mys1, Q, 64); \
        float4 gA = *(const float4*)(gl + Q * 8); \
        float4 gB = *(const float4*)(gl + Q * 8 + 4); \
        G2 g; \
        g.Ax = gA.x * cc + gA.z * ss;  g.Ay = gA.y * cc + gA.w * ss; \
        g.Az = gA.z * cc - gA.x * ss;  g.Aw = gA.w * cc - gA.y * ss; \
        g.Bx = gB.x * cc + gB.z * ss;  g.By = gB.y * cc + gB.w * ss; \
        g.Bz = gB.z * cc - gB.x * ss;  g.Bw = gB.w * cc - gB.y * ss; \
        GATECALL; }
        FROTQ(0, (rot_gate_pl_c<32>(re, im, g)))        // P=9
        FROTQ(1, (rot_gate_pl_c<16>(re, im, g)))        // P=8
        FROTQ(2, (rot_gate_c<7>(re, im, lane, g)))
        FROTQ(3, (rot_gate_c<6>(re, im, lane, g)))
        FROTQ(4, (rot_gate_c<5>(re, im, lane, g)))
        FROTQ(5, (rot_gate_c<4>(re, im, lane, g)))
        FROTQ(6, (rot_gate_c<3>(re, im, lane, g)))
        FROTQ(7, (rot_gate_c<2>(re, im, lane, g)))
        FROTQ(8, (rot_gate_c<1>(re, im, lane, g)))
        FROTQ(9, (rot_gate_c<0>(re, im, lane, g)))
#undef FROTQ
        // CNOT ring (9,8)..(5,4) as one lane permutation
#pragma unroll
        for (int r = 0; r < 16; r++) {
            re[r].x = __int_as_float(__builtin_amdgcn_ds_bpermute(bidx, __float_as_int(re[r].x)));
            re[r].y = __int_as_float(__builtin_amdgcn_ds_bpermute(bidx, __float_as_int(re[r].y)));
            im[r].x = __int_as_float(__builtin_amdgcn_ds_bpermute(bidx, __float_as_int(im[r].x)));
            im[r].y = __int_as_float(__builtin_amdgcn_ds_bpermute(bidx, __float_as_int(im[r].y)));
        }
        cnot_gate_c<4, 3>(re, im, lane);
        cnot_gate_c<3, 2>(re, im, lane);
        cnot_gate_c<2, 1>(re, im, lane);
        cnot_gate_c<1, 0>(re, im, lane);
        // cnot<0,9> fused into next layer's rot<9>
    }

    // ---- layers 1..3 (first gate consumes previous layer's trailing cnot<0,9>) ----
    for (int l = 1; l < NLAYERS; l++) {
        const float* gl = &gates[l * NQ * 8];
        { G2 g = load_g(gl, 0); rot9_fused_c(re, im, lane, g); }
        { G2 g = load_g(gl, 1); rot_gate_pl_c<16>(re, im, g); }   // P=8
        { G2 g = load_g(gl, 2); rot_gate_c<7>(re, im, lane, g); }
        { G2 g = load_g(gl, 3); rot_gate_c<6>(re, im, lane, g); }
        { G2 g = load_g(gl, 4); rot_gate_c<5>(re, im, lane, g); }
        { G2 g = load_g(gl, 5); rot_gate_c<4>(re, im, lane, g); }
        { G2 g = load_g(gl, 6); rot_gate_c<3>(re, im, lane, g); }
        { G2 g = load_g(gl, 7); rot_gate_c<2>(re, im, lane, g); }
        { G2 g = load_g(gl, 8); rot_gate_c<1>(re, im, lane, g); }
        { G2 g = load_g(gl, 9); rot_gate_c<0>(re, im, lane, g); }
#pragma unroll
        for (int r = 0; r < 16; r++) {
            re[r].x = __int_as_float(__builtin_amdgcn_ds_bpermute(bidx, __float_as_int(re[r].x)));
            re[r].y = __int_as_float(__builtin_amdgcn_ds_bpermute(bidx, __float_as_int(re[r].y)));
            im[r].x = __int_as_float(__builtin_amdgcn_ds_bpermute(bidx, __float_as_int(im[r].x)));
            im[r].y = __int_as_float(__builtin_amdgcn_ds_bpermute(bidx, __float_as_int(im[r].y)));
        }
        cnot_gate_c<4, 3>(re, im, lane);
        cnot_gate_c<3, 2>(re, im, lane);
        cnot_gate_c<2, 1>(re, im, lane);
        cnot_gate_c<1, 0>(re, im, lane);
    }
    // layer 3's trailing cnot<0,9> applied for real (measurement follows)
    cnot_gate_c<0, 9>(re, im, lane);

    // ---- measurement: Z expectation per qubit, both states packed ----
    f2 S = sp(0.f), z3 = sp(0.f), z2 = sp(0.f), z1 = sp(0.f), z0 = sp(0.f);
#pragma unroll
    for (int r = 0; r < 16; r++) {
        f2 pa = re[r] * re[r] + im[r] * im[r];
        S += pa;
        if (r & 8) z3 -= pa; else z3 += pa;
        if (r & 4) z2 -= pa; else z2 += pa;
        if (r & 2) z1 -= pa; else z1 += pa;
        if (r & 1) z0 -= pa; else z0 += pa;
    }
    f2 zq[NQ];
    zq[6] = z3; zq[7] = z2; zq[8] = z1; zq[9] = z0;
#pragma unroll
    for (int q = 0; q < 6; q++) {                      // lane qubits: lane bit 5-q
        zq[q] = ((lane >> (5 - q)) & 1) ? -S : S;
    }
#pragma unroll
    for (int q = 0; q < NQ; q++) {
#pragma unroll
        for (int o = 1; o < 64; o <<= 1) {
            zq[q].x += __shfl_xor(zq[q].x, o, 64);
            zq[q].y += __shfl_xor(zq[q].y, o, 64);
        }
    }

    // ---- output projection: out = zq @ Wo^T + bo, both states ----
    if (lane < NQ) {
        const float* wrow = Wo + lane * NQ;
        float o0 = bo[lane], o1 = o0;
#pragma unroll
        for (int q = 0; q < NQ; q++) {
            float w = wrow[q];
            o0 += zq[q].x * w;
            o1 += zq[q].y * w;
        }
        out[(size_t)s0 * NQ + lane] = o0;
        out[(size_t)s1 * NQ + lane] = o1;
    }
}

extern "C" void kernel_launch(void* const* d_in, const int* in_sizes, int n_in,
                              void* d_out, int out_size, void* d_ws, size_t ws_size,
                              hipStream_t stream) {
    const float* x  = (const float*)d_in[0];
    const float* Wp = (const float*)d_in[1];
    const float* bp = (const float*)d_in[2];
    const float* qw = (const float*)d_in[3];
    const float* Wo = (const float*)d_in[4];
    const float* bo = (const float*)d_in[5];
    float* out = (float*)d_out;

    const int B = in_sizes[0] / D_IN;                  // 8192 states, two per wave
    const int waves = (B + 1) / 2;
    const int spb = BLOCK / 64;                        // waves per block (4)
    const int blocks = (waves + spb - 1) / spb;
    hipLaunchKernelGGL(qnet_kernel, dim3(blocks), dim3(BLOCK), 0, stream,
                       x, Wp, bp, qw, Wo, bo, out, B);
}